// Round 10
// baseline (309.228 us; speedup 1.0000x reference)
//
#include <hip/hip_runtime.h>
#include <hip/hip_bf16.h>
#include <math.h>

#define NTRI 69
#define NB 128
#define NGRP 64            // batch pairs for sumsq partials
#define IN_LEN 864
#define MS_LEN 39744
#define EPSV 1e-5f

typedef short short8 __attribute__((ext_vector_type(8)));
typedef float f32x4 __attribute__((ext_vector_type(4)));
typedef __hip_bfloat16 bf16;

// ---- compile-time triple tables ----
struct Tables { int l1[NTRI], l2[NTRI], lo[NTRI], tpos[NTRI], cgoff[NTRI], ncg; };
constexpr Tables make_tables(){
  Tables t{};
  int cnt[6]={0,0,0,0,0,0}; int n=0, ncg=0;
  for(int a=0;a<=5;++a)
    for(int b=0;b<=a;++b)
      for(int l=a-b; l<=((a+b<5)?(a+b):5); ++l){
        t.l1[n]=a; t.l2[n]=b; t.lo[n]=l; t.tpos[n]=cnt[l]++;
        t.cgoff[n]=ncg; ncg+=(2*l+1)*(2*a+1); ++n;
      }
  t.ncg=ncg; return t;
}
constexpr Tables TB = make_tables();
constexpr int MT[6]   = {3456,5760,7488,8064,8064,6912};
constexpr int MSOFF[7]= {0,3456,9216,16704,24768,32832,39744};

struct MPar {
  int bb[NTRI];                 // B column base (elements): boff[l]+tpos*1152 (interleaved K)
  int gch[NTRI];                // global middle-channel base
  unsigned char otri[NTRI];     // heavy-first block order
};
struct CMeta { unsigned char l1[NTRI], l2[NTRI], lo[NTRI]; int cg_off[NTRI]; };
struct GMeta { int aoff[6], boff[6], K[6], mt[6], w_off[6], ms_off[7], tb[7]; };

__constant__ double c_fac[18] = {
  1.0,1.0,2.0,6.0,24.0,120.0,720.0,5040.0,40320.0,362880.0,3628800.0,
  39916800.0,479001600.0,6227020800.0,87178291200.0,1307674368000.0,
  20922789888000.0,355687428096000.0 };

__device__ double cg_coef(int j1,int m1,int j2,int m2,int j,int m){
  if (m1+m2!=m) return 0.0;
  double pref = sqrt((2.0*j+1.0)*c_fac[j+j1-j2]*c_fac[j-j1+j2]*c_fac[j1+j2-j]/c_fac[j1+j2+j+1]);
  pref *= sqrt(c_fac[j+m]*c_fac[j-m]*c_fac[j1-m1]*c_fac[j1+m1]*c_fac[j2-m2]*c_fac[j2+m2]);
  int kmin = max(0, max(-(j-j2+m1), -(j-j1-m2)));
  int kmax = min(j1+j2-j, min(j1-m1, j2+m2));
  double s = 0.0;
  for (int k=kmin;k<=kmax;++k){
    double d = c_fac[k]*c_fac[j1+j2-j-k]*c_fac[j1-m1-k]*c_fac[j2+m2-k]*c_fac[j-j2+m1+k]*c_fac[j-j1-m2+k];
    s += ((k&1)? -1.0:1.0)/d;
  }
  return pref*s;
}

__global__ void k_init_cg(float* __restrict__ cg, CMeta cm){
  int tri = blockIdx.x;
  int l1=cm.l1[tri], l2=cm.l2[tri], l=cm.lo[tri];
  int n1=2*l1+1, nm=2*l+1;
  int n=nm*n1;
  for (int e=threadIdx.x; e<n; e+=blockDim.x){
    int mi=e/n1, xi=e-mi*n1;
    int m=mi-l, m1=xi-l1, m2=m-m1;
    float v=0.f;
    if (m2>=-l2 && m2<=l2) v=(float)cg_coef(l1,m1,l2,m2,l,m);
    cg[cm.cg_off[tri]+e]=v;
  }
}

// ---- per-TRIPLE middle kernel: R6 body + 2-batch inner loop ----
// one thread = (channel, 2 batches); store pattern per batch identical to R6.
template<int TRI>
__device__ __forceinline__ void mid_body(
    const float2* __restrict__ act, const float* __restrict__ cg,
    bf16* __restrict__ Bm, float* __restrict__ partial,
    const MPar& mp, int ts, int b0, float* cgl)
{
  constexpr int L1=TB.l1[TRI], L2=TB.l2[TRI], L=TB.lo[TRI];
  constexpr int N1=2*L1+1, N2=2*L2+1, NM=2*L+1;
  constexpr int D=L1+L2-L;
  constexpr int MTL=MT[L], KL=2*MTL;
  for (int i=threadIdx.x; i<NM*N1; i+=192) cgl[i]=cg[TB.cgoff[TRI]+i];
  __syncthreads();
  int t=ts/24, s=ts-24*t;
  const int a1=24*L1*L1+t*N1, a2=24*L2*L2+s*N2;
  float ss=0.f;
  const int bbase=mp.bb[TRI];
  #pragma unroll 1
  for (int bi=0;bi<2;++bi){
    const int brel=(int)blockIdx.y*2+bi;
    const int b=b0+brel;
    const float2* ab=act+(size_t)b*IN_LEN;
    float f1r[N1],f1i[N1],f2r[N2],f2i[N2];
    #pragma unroll
    for (int x=0;x<N1;++x){ float2 v=ab[a1+x]; f1r[x]=v.x; f1i[x]=v.y; }
    #pragma unroll
    for (int y=0;y<N2;++y){ float2 v=ab[a2+y]; f2r[y]=v.x; f2i[y]=v.y; }
    size_t rowb=(size_t)bbase+(size_t)brel*NM*KL+2*ts;
    #pragma unroll
    for (int m=0;m<NM;++m){
      float fr=0.f, fi=0.f;
      #pragma unroll
      for (int x=0;x<N1;++x){
        const int y=m-x+D;
        if (y>=0 && y<N2){
          float cv=cgl[m*N1+x];
          fr += cv*(f1r[x]*f2r[y]-f1i[x]*f2i[y]);
          fi += cv*(f1r[x]*f2i[y]+f1i[x]*f2r[y]);
        }
      }
      ss += fr*fr+fi*fi;
      union { bf16 h[2]; unsigned u; } pk;
      pk.h[0]=__float2bfloat16(fr); pk.h[1]=__float2bfloat16(fi);
      *reinterpret_cast<unsigned*>(Bm+rowb+(size_t)m*KL)=pk.u;
    }
  }
  partial[(size_t)((b0>>1)+blockIdx.y)*MS_LEN + mp.gch[TRI] + ts] = ss;
}

__global__ __launch_bounds__(192,4)
void k_mid3(const float2* __restrict__ act, const float* __restrict__ cg,
            bf16* __restrict__ Bm, float* __restrict__ partial, MPar mp, int b0){
  __shared__ float cgl[121];
  int bx=blockIdx.x;
  int tri = mp.otri[bx/3], seg = bx - (bx/3)*3;
  int ts = seg*192 + threadIdx.x;
  #define CASE(T) case T: mid_body<T>(act,cg,Bm,partial,mp,ts,b0,cgl); break;
  switch(tri){
    CASE(0) CASE(1) CASE(2) CASE(3) CASE(4) CASE(5) CASE(6) CASE(7) CASE(8)
    CASE(9) CASE(10) CASE(11) CASE(12) CASE(13) CASE(14) CASE(15) CASE(16)
    CASE(17) CASE(18) CASE(19) CASE(20) CASE(21) CASE(22) CASE(23) CASE(24)
    CASE(25) CASE(26) CASE(27) CASE(28) CASE(29) CASE(30) CASE(31) CASE(32)
    CASE(33) CASE(34) CASE(35) CASE(36) CASE(37) CASE(38) CASE(39) CASE(40)
    CASE(41) CASE(42) CASE(43) CASE(44) CASE(45) CASE(46) CASE(47) CASE(48)
    CASE(49) CASE(50) CASE(51) CASE(52) CASE(53) CASE(54) CASE(55) CASE(56)
    CASE(57) CASE(58) CASE(59) CASE(60) CASE(61) CASE(62) CASE(63) CASE(64)
    CASE(65) CASE(66) CASE(67) CASE(68)
    default: break;
  }
  #undef CASE
}

// fused: per-channel scale computation + scaled stacked-real A build
__global__ __launch_bounds__(256)
void k_scaleA(const float* __restrict__ partial, const float* __restrict__ mstd,
              const float2* __restrict__ wts, bf16* __restrict__ Am, GMeta gm){
  int c=blockIdx.x*256+threadIdx.x;
  if (c>=MS_LEN) return;
  int l=0;
  #pragma unroll
  for (int i=1;i<6;++i) if (c>=gm.ms_off[i]) l=i;
  float ss=0.f;
  for (int g=0;g<NGRP;++g) ss += partial[(size_t)g*MS_LEN+c];
  float bstd = sqrtf(ss/(128.f*(float)(2*l+1)));
  float s = 1.f/(0.5f*(mstd[c]+bstd)+EPSV);
  int mt=gm.mt[l];
  int cl=c-gm.ms_off[l];
  size_t K=(size_t)gm.K[l];
  bf16* Al=Am+gm.aoff[l];
  const float2* Wl=wts+gm.w_off[l];
  #pragma unroll 4
  for (int o=0;o<24;++o){
    float2 w=Wl[(size_t)o*mt+cl];
    union { bf16 h[2]; unsigned u; } p0, p1;
    p0.h[0]=__float2bfloat16(w.x*s);  p0.h[1]=__float2bfloat16(-w.y*s);
    p1.h[0]=__float2bfloat16(w.y*s);  p1.h[1]=__float2bfloat16(w.x*s);
    *reinterpret_cast<unsigned*>(Al+(size_t)o*K+2*cl)      = p0.u;
    *reinterpret_cast<unsigned*>(Al+(size_t)(24+o)*K+2*cl) = p1.u;
  }
}

// GEMM with K split over blockIdx.y into 4 chunks; per-chunk 48x16 tile -> part
__global__ __launch_bounds__(256)
void k_gemm2(const bf16* __restrict__ Am, const bf16* __restrict__ Bm,
             float* __restrict__ part, GMeta gm){
  int bid=blockIdx.x, z=blockIdx.y;
  int l=0;
  #pragma unroll
  for (int i=1;i<6;++i) if (bid>=gm.tb[i]) l=i;
  int ntile=bid-gm.tb[l];
  int K=gm.K[l];
  int tid=threadIdx.x, lane=tid&63, w=tid>>6;
  int r=lane&15, kg=lane>>4;
  int nit=K>>7;
  int nz=(nit+3)>>2;
  int it0=z*nz, it1=(nit<it0+nz)?nit:(it0+nz);
  f32x4 acc0={0.f,0.f,0.f,0.f}, acc1=acc0, acc2=acc0;
  __shared__ float red[3072];
  if (it0<it1){
    const bf16* Al=Am+gm.aoff[l];
    const bf16* Bl=Bm+gm.boff[l];
    size_t koff=(size_t)(w*32+kg*8)+(size_t)it0*128;
    const short8* pa0=(const short8*)(Al+(size_t)r*K+koff);
    const short8* pa1=(const short8*)(Al+(size_t)(16+r)*K+koff);
    const short8* pa2=(const short8*)(Al+(size_t)(32+r)*K+koff);
    const short8* pb =(const short8*)(Bl+(size_t)(ntile*16+r)*K+koff);
    short8 ca0=*pa0, ca1=*pa1, ca2=*pa2, cb=*pb;
    for (int it=it0+1; it<it1; ++it){
      pa0+=16; pa1+=16; pa2+=16; pb+=16;
      short8 na0=*pa0, na1=*pa1, na2=*pa2, nb_=*pb;
      acc0=__builtin_amdgcn_mfma_f32_16x16x32_bf16(ca0,cb,acc0,0,0,0);
      acc1=__builtin_amdgcn_mfma_f32_16x16x32_bf16(ca1,cb,acc1,0,0,0);
      acc2=__builtin_amdgcn_mfma_f32_16x16x32_bf16(ca2,cb,acc2,0,0,0);
      ca0=na0; ca1=na1; ca2=na2; cb=nb_;
    }
    acc0=__builtin_amdgcn_mfma_f32_16x16x32_bf16(ca0,cb,acc0,0,0,0);
    acc1=__builtin_amdgcn_mfma_f32_16x16x32_bf16(ca1,cb,acc1,0,0,0);
    acc2=__builtin_amdgcn_mfma_f32_16x16x32_bf16(ca2,cb,acc2,0,0,0);
  }
  #pragma unroll
  for (int reg=0;reg<4;++reg){
    int row0=kg*4+reg;
    red[(w*48+row0)*16+r]     =acc0[reg];
    red[(w*48+16+row0)*16+r]  =acc1[reg];
    red[(w*48+32+row0)*16+r]  =acc2[reg];
  }
  __syncthreads();
  float* po = part + (size_t)(bid*4+z)*768;
  for (int e=tid;e<768;e+=256)
    po[e]=red[e]+red[768+e]+red[1536+e]+red[2304+e];
}

__global__ __launch_bounds__(256)
void k_red(const float* __restrict__ part, float* __restrict__ outf,
           GMeta gm, int b0){
  int bid=blockIdx.x;
  int l=0;
  #pragma unroll
  for (int i=1;i<6;++i) if (bid>=gm.tb[i]) l=i;
  int ntile=bid-gm.tb[l];
  int nm=2*l+1;
  const float* po = part + (size_t)bid*4*768;
  for (int e=threadIdx.x;e<768;e+=256){
    float sv=po[e]+po[768+e]+po[1536+e]+po[2304+e];
    int o=e>>4, cc=e&15;
    int n=ntile*16+cc;
    int bb=n/nm, m=n-bb*nm;
    int b=b0+bb;
    int oo=(o<24)?o:(o-24);
    int comp=(o<24)?0:1;
    outf[((size_t)b*IN_LEN + 24*l*l + oo*nm + m)*2 + comp]=sv;
  }
}

extern "C" void kernel_launch(void* const* d_in, const int* in_sizes, int n_in,
                              void* d_out, int out_size, void* d_ws, size_t ws_size,
                              hipStream_t stream) {
  const float2* act  = (const float2*)d_in[0];
  const float2* wts  = (const float2*)d_in[1];
  const float*  mstd = (const float*)d_in[2];
  float* outf = (float*)d_out;
  (void)in_sizes; (void)n_in; (void)out_size;

  GMeta gm; CMeta cm; MPar mp;
  for (int l=0;l<6;++l){ gm.mt[l]=MT[l]; gm.K[l]=2*MT[l]; }
  for (int l=0;l<7;++l) gm.ms_off[l]=MSOFF[l];
  for (int l=0;l<6;++l) gm.w_off[l]=24*gm.ms_off[l];
  int atot=0;
  for (int l=0;l<6;++l){ gm.aoff[l]=atot; atot+=48*gm.K[l]; }
  for (int i=0;i<NTRI;++i){
    cm.l1[i]=(unsigned char)TB.l1[i]; cm.l2[i]=(unsigned char)TB.l2[i];
    cm.lo[i]=(unsigned char)TB.lo[i]; cm.cg_off[i]=TB.cgoff[i];
    mp.gch[i]=MSOFF[TB.lo[i]]+TB.tpos[i]*576;
  }
  int ncg=TB.ncg;

  // heavy-first block order
  {
    int ordt[NTRI];
    for (int i=0;i<NTRI;++i) ordt[i]=i;
    for (int i=1;i<NTRI;++i){
      int v=ordt[i];
      int wv=(2*TB.lo[v]+1)*(2*TB.l1[v]+1);
      int j=i-1;
      while (j>=0){
        int wj=(2*TB.lo[ordt[j]]+1)*(2*TB.l1[ordt[j]]+1);
        if (wj>=wv) break;
        ordt[j+1]=ordt[j]; --j;
      }
      ordt[j+1]=v;
    }
    for (int i=0;i<NTRI;++i) mp.otri[i]=(unsigned char)ordt[i];
  }

  // ---- ws layout ----
  size_t ob=0;
  auto alloc=[&](size_t bytes){ size_t o=ob; ob=(ob+bytes+255)&~255ULL; return o; };
  size_t off_cg      = alloc((size_t)ncg*4);
  size_t off_partial = alloc((size_t)NGRP*MS_LEN*4);
  size_t off_A       = alloc((size_t)atot*2);
  size_t off_part    = alloc((size_t)288*4*768*4);
  size_t off_B       = ob;

  size_t perB=0;
  for (int l=0;l<6;++l) perB += (size_t)(2*l+1)*gm.K[l]*2;
  int nb=16;
  for (int cand : {128,64,32,16})
    if (off_B + (size_t)cand*perB <= ws_size){ nb=cand; break; }

  { int bo=0; for (int l=0;l<6;++l){ gm.boff[l]=bo; bo+=nb*(2*l+1)*gm.K[l]; } }
  gm.tb[0]=0;
  for (int l=0;l<6;++l) gm.tb[l+1]=gm.tb[l]+nb*(2*l+1)/16;
  for (int i=0;i<NTRI;++i)
    mp.bb[i] = gm.boff[TB.lo[i]] + TB.tpos[i]*1152;   // column base, interleaved K

  uint8_t* wsb=(uint8_t*)d_ws;
  float* cg      =(float*)(wsb+off_cg);
  float* partial =(float*)(wsb+off_partial);
  bf16*  Am      =(bf16*)(wsb+off_A);
  float* part    =(float*)(wsb+off_part);
  bf16*  Bm      =(bf16*)(wsb+off_B);

  k_init_cg<<<NTRI,64,0,stream>>>(cg, cm);
  int tiles=gm.tb[6];
  if (nb==NB){
    k_mid3<<<dim3(NTRI*3,NB/2),192,0,stream>>>(act,cg,Bm,partial,mp,0);
    k_scaleA<<<(MS_LEN+255)/256,256,0,stream>>>(partial,mstd,wts,Am,gm);
    k_gemm2<<<dim3(tiles,4),256,0,stream>>>(Am,Bm,part,gm);
    k_red<<<tiles,256,0,stream>>>(part,outf,gm,0);
  } else {
    for (int b0=0;b0<NB;b0+=nb)
      k_mid3<<<dim3(NTRI*3,nb/2),192,0,stream>>>(act,cg,Bm,partial,mp,b0);
    k_scaleA<<<(MS_LEN+255)/256,256,0,stream>>>(partial,mstd,wts,Am,gm);
    for (int b0=0;b0<NB;b0+=nb){
      k_mid3<<<dim3(NTRI*3,nb/2),192,0,stream>>>(act,cg,Bm,partial,mp,b0);
      k_gemm2<<<dim3(tiles,4),256,0,stream>>>(Am,Bm,part,gm);
      k_red<<<tiles,256,0,stream>>>(part,outf,gm,b0);
    }
  }
}

// Round 11
// 192.621 us; speedup vs baseline: 1.6054x; 1.6054x over previous
//
#include <hip/hip_runtime.h>
#include <hip/hip_bf16.h>
#include <math.h>

#define NTRI 69
#define NB 128
#define IN_LEN 864
#define MS_LEN 39744
#define EPSV 1e-5f

typedef short short8 __attribute__((ext_vector_type(8)));
typedef float f32x4 __attribute__((ext_vector_type(4)));
typedef __hip_bfloat16 bf16;

// ---- compile-time triple tables ----
struct Tables { int l1[NTRI], l2[NTRI], lo[NTRI], tpos[NTRI], cgoff[NTRI], ncg; };
constexpr Tables make_tables(){
  Tables t{};
  int cnt[6]={0,0,0,0,0,0}; int n=0, ncg=0;
  for(int a=0;a<=5;++a)
    for(int b=0;b<=a;++b)
      for(int l=a-b; l<=((a+b<5)?(a+b):5); ++l){
        t.l1[n]=a; t.l2[n]=b; t.lo[n]=l; t.tpos[n]=cnt[l]++;
        t.cgoff[n]=ncg; ncg+=(2*l+1)*(2*a+1); ++n;
      }
  t.ncg=ncg; return t;
}
constexpr Tables TB = make_tables();
constexpr int MT[6]   = {3456,5760,7488,8064,8064,6912};
constexpr int MSOFF[7]= {0,3456,9216,16704,24768,32832,39744};

struct MPar {
  int bb[NTRI];                 // B column base (elements): boff[l]+tpos*1152 (interleaved K)
  int gch[NTRI];                // global middle-channel base
  unsigned char otri[NTRI];     // heavy-first block order
};
struct CMeta { unsigned char l1[NTRI], l2[NTRI], lo[NTRI]; int cg_off[NTRI]; };
struct GMeta { int aoff[6], boff[6], K[6], mt[6], w_off[6], ms_off[7], tb[7]; };

__constant__ double c_fac[18] = {
  1.0,1.0,2.0,6.0,24.0,120.0,720.0,5040.0,40320.0,362880.0,3628800.0,
  39916800.0,479001600.0,6227020800.0,87178291200.0,1307674368000.0,
  20922789888000.0,355687428096000.0 };

__device__ double cg_coef(int j1,int m1,int j2,int m2,int j,int m){
  if (m1+m2!=m) return 0.0;
  double pref = sqrt((2.0*j+1.0)*c_fac[j+j1-j2]*c_fac[j-j1+j2]*c_fac[j1+j2-j]/c_fac[j1+j2+j+1]);
  pref *= sqrt(c_fac[j+m]*c_fac[j-m]*c_fac[j1-m1]*c_fac[j1+m1]*c_fac[j2-m2]*c_fac[j2+m2]);
  int kmin = max(0, max(-(j-j2+m1), -(j-j1-m2)));
  int kmax = min(j1+j2-j, min(j1-m1, j2+m2));
  double s = 0.0;
  for (int k=kmin;k<=kmax;++k){
    double d = c_fac[k]*c_fac[j1+j2-j-k]*c_fac[j1-m1-k]*c_fac[j2+m2-k]*c_fac[j-j2+m1+k]*c_fac[j-j1-m2+k];
    s += ((k&1)? -1.0:1.0)/d;
  }
  return pref*s;
}

__global__ void k_init_cg(float* __restrict__ cg, CMeta cm){
  int tri = blockIdx.x;
  int l1=cm.l1[tri], l2=cm.l2[tri], l=cm.lo[tri];
  int n1=2*l1+1, nm=2*l+1;
  int n=nm*n1;
  for (int e=threadIdx.x; e<n; e+=blockDim.x){
    int mi=e/n1, xi=e-mi*n1;
    int m=mi-l, m1=xi-l1, m2=m-m1;
    float v=0.f;
    if (m2>=-l2 && m2<=l2) v=(float)cg_coef(l1,m1,l2,m2,l,m);
    cg[cm.cg_off[tri]+e]=v;
  }
}

// ---- per-TRIPLE middle kernel: 576 threads = all channels of one (triple,batch);
//      per-thread body byte-identical to round 6 (1 batch, one dword store per m). ----
template<int TRI>
__device__ __forceinline__ void mid_body(
    const float2* __restrict__ act, const float* __restrict__ cg,
    bf16* __restrict__ Bm, float* __restrict__ partial,
    const MPar& mp, int b0, float* cgl)
{
  constexpr int L1=TB.l1[TRI], L2=TB.l2[TRI], L=TB.lo[TRI];
  constexpr int N1=2*L1+1, N2=2*L2+1, NM=2*L+1;
  constexpr int D=L1+L2-L;
  constexpr int MTL=MT[L], KL=2*MTL;
  for (int i=threadIdx.x; i<NM*N1; i+=576) cgl[i]=cg[TB.cgoff[TRI]+i];
  __syncthreads();
  const int ts=threadIdx.x;
  int t=ts/24, s=ts-24*t;
  const int a1=24*L1*L1+t*N1, a2=24*L2*L2+s*N2;
  const int brel=(int)blockIdx.y;
  const int b=b0+brel;
  const float2* ab=act+(size_t)b*IN_LEN;
  float f1r[N1],f1i[N1],f2r[N2],f2i[N2];
  #pragma unroll
  for (int x=0;x<N1;++x){ float2 v=ab[a1+x]; f1r[x]=v.x; f1i[x]=v.y; }
  #pragma unroll
  for (int y=0;y<N2;++y){ float2 v=ab[a2+y]; f2r[y]=v.x; f2i[y]=v.y; }
  float ss=0.f;
  size_t rowb=(size_t)mp.bb[TRI]+(size_t)brel*NM*KL+2*ts;
  #pragma unroll
  for (int m=0;m<NM;++m){
    float fr=0.f, fi=0.f;
    #pragma unroll
    for (int x=0;x<N1;++x){
      const int y=m-x+D;
      if (y>=0 && y<N2){
        float cv=cgl[m*N1+x];
        fr += cv*(f1r[x]*f2r[y]-f1i[x]*f2i[y]);
        fi += cv*(f1r[x]*f2i[y]+f1i[x]*f2r[y]);
      }
    }
    ss += fr*fr+fi*fi;
    union { bf16 h[2]; unsigned u; } pk;
    pk.h[0]=__float2bfloat16(fr); pk.h[1]=__float2bfloat16(fi);
    *reinterpret_cast<unsigned*>(Bm+rowb+(size_t)m*KL)=pk.u;
  }
  partial[(size_t)b*MS_LEN + mp.gch[TRI] + ts] = ss;
}

__global__ __launch_bounds__(576)
void k_mid3(const float2* __restrict__ act, const float* __restrict__ cg,
            bf16* __restrict__ Bm, float* __restrict__ partial, MPar mp, int b0){
  __shared__ float cgl[121];
  int tri = mp.otri[blockIdx.x];
  #define CASE(T) case T: mid_body<T>(act,cg,Bm,partial,mp,b0,cgl); break;
  switch(tri){
    CASE(0) CASE(1) CASE(2) CASE(3) CASE(4) CASE(5) CASE(6) CASE(7) CASE(8)
    CASE(9) CASE(10) CASE(11) CASE(12) CASE(13) CASE(14) CASE(15) CASE(16)
    CASE(17) CASE(18) CASE(19) CASE(20) CASE(21) CASE(22) CASE(23) CASE(24)
    CASE(25) CASE(26) CASE(27) CASE(28) CASE(29) CASE(30) CASE(31) CASE(32)
    CASE(33) CASE(34) CASE(35) CASE(36) CASE(37) CASE(38) CASE(39) CASE(40)
    CASE(41) CASE(42) CASE(43) CASE(44) CASE(45) CASE(46) CASE(47) CASE(48)
    CASE(49) CASE(50) CASE(51) CASE(52) CASE(53) CASE(54) CASE(55) CASE(56)
    CASE(57) CASE(58) CASE(59) CASE(60) CASE(61) CASE(62) CASE(63) CASE(64)
    CASE(65) CASE(66) CASE(67) CASE(68)
    default: break;
  }
  #undef CASE
}

// fused: per-channel scale computation + scaled stacked-real A build
__global__ __launch_bounds__(256)
void k_scaleA(const float* __restrict__ partial, const float* __restrict__ mstd,
              const float2* __restrict__ wts, bf16* __restrict__ Am, GMeta gm){
  int c=blockIdx.x*256+threadIdx.x;
  if (c>=MS_LEN) return;
  int l=0;
  #pragma unroll
  for (int i=1;i<6;++i) if (c>=gm.ms_off[i]) l=i;
  float ss=0.f;
  for (int g=0;g<NB;++g) ss += partial[(size_t)g*MS_LEN+c];
  float bstd = sqrtf(ss/(128.f*(float)(2*l+1)));
  float s = 1.f/(0.5f*(mstd[c]+bstd)+EPSV);
  int mt=gm.mt[l];
  int cl=c-gm.ms_off[l];
  size_t K=(size_t)gm.K[l];
  bf16* Al=Am+gm.aoff[l];
  const float2* Wl=wts+gm.w_off[l];
  #pragma unroll 4
  for (int o=0;o<24;++o){
    float2 w=Wl[(size_t)o*mt+cl];
    union { bf16 h[2]; unsigned u; } p0, p1;
    p0.h[0]=__float2bfloat16(w.x*s);  p0.h[1]=__float2bfloat16(-w.y*s);
    p1.h[0]=__float2bfloat16(w.y*s);  p1.h[1]=__float2bfloat16(w.x*s);
    *reinterpret_cast<unsigned*>(Al+(size_t)o*K+2*cl)      = p0.u;
    *reinterpret_cast<unsigned*>(Al+(size_t)(24+o)*K+2*cl) = p1.u;
  }
}

// GEMM with K split over blockIdx.y into 4 chunks; per-chunk 48x16 tile -> part
__global__ __launch_bounds__(256)
void k_gemm2(const bf16* __restrict__ Am, const bf16* __restrict__ Bm,
             float* __restrict__ part, GMeta gm){
  int bid=blockIdx.x, z=blockIdx.y;
  int l=0;
  #pragma unroll
  for (int i=1;i<6;++i) if (bid>=gm.tb[i]) l=i;
  int ntile=bid-gm.tb[l];
  int K=gm.K[l];
  int tid=threadIdx.x, lane=tid&63, w=tid>>6;
  int r=lane&15, kg=lane>>4;
  int nit=K>>7;
  int nz=(nit+3)>>2;
  int it0=z*nz, it1=(nit<it0+nz)?nit:(it0+nz);
  f32x4 acc0={0.f,0.f,0.f,0.f}, acc1=acc0, acc2=acc0;
  __shared__ float red[3072];
  if (it0<it1){
    const bf16* Al=Am+gm.aoff[l];
    const bf16* Bl=Bm+gm.boff[l];
    size_t koff=(size_t)(w*32+kg*8)+(size_t)it0*128;
    const short8* pa0=(const short8*)(Al+(size_t)r*K+koff);
    const short8* pa1=(const short8*)(Al+(size_t)(16+r)*K+koff);
    const short8* pa2=(const short8*)(Al+(size_t)(32+r)*K+koff);
    const short8* pb =(const short8*)(Bl+(size_t)(ntile*16+r)*K+koff);
    short8 ca0=*pa0, ca1=*pa1, ca2=*pa2, cb=*pb;
    for (int it=it0+1; it<it1; ++it){
      pa0+=16; pa1+=16; pa2+=16; pb+=16;
      short8 na0=*pa0, na1=*pa1, na2=*pa2, nb_=*pb;
      acc0=__builtin_amdgcn_mfma_f32_16x16x32_bf16(ca0,cb,acc0,0,0,0);
      acc1=__builtin_amdgcn_mfma_f32_16x16x32_bf16(ca1,cb,acc1,0,0,0);
      acc2=__builtin_amdgcn_mfma_f32_16x16x32_bf16(ca2,cb,acc2,0,0,0);
      ca0=na0; ca1=na1; ca2=na2; cb=nb_;
    }
    acc0=__builtin_amdgcn_mfma_f32_16x16x32_bf16(ca0,cb,acc0,0,0,0);
    acc1=__builtin_amdgcn_mfma_f32_16x16x32_bf16(ca1,cb,acc1,0,0,0);
    acc2=__builtin_amdgcn_mfma_f32_16x16x32_bf16(ca2,cb,acc2,0,0,0);
  }
  #pragma unroll
  for (int reg=0;reg<4;++reg){
    int row0=kg*4+reg;
    red[(w*48+row0)*16+r]     =acc0[reg];
    red[(w*48+16+row0)*16+r]  =acc1[reg];
    red[(w*48+32+row0)*16+r]  =acc2[reg];
  }
  __syncthreads();
  float* po = part + (size_t)(bid*4+z)*768;
  for (int e=tid;e<768;e+=256)
    po[e]=red[e]+red[768+e]+red[1536+e]+red[2304+e];
}

__global__ __launch_bounds__(256)
void k_red(const float* __restrict__ part, float* __restrict__ outf,
           GMeta gm, int b0){
  int bid=blockIdx.x;
  int l=0;
  #pragma unroll
  for (int i=1;i<6;++i) if (bid>=gm.tb[i]) l=i;
  int ntile=bid-gm.tb[l];
  int nm=2*l+1;
  const float* po = part + (size_t)bid*4*768;
  for (int e=threadIdx.x;e<768;e+=256){
    float sv=po[e]+po[768+e]+po[1536+e]+po[2304+e];
    int o=e>>4, cc=e&15;
    int n=ntile*16+cc;
    int bb=n/nm, m=n-bb*nm;
    int b=b0+bb;
    int oo=(o<24)?o:(o-24);
    int comp=(o<24)?0:1;
    outf[((size_t)b*IN_LEN + 24*l*l + oo*nm + m)*2 + comp]=sv;
  }
}

extern "C" void kernel_launch(void* const* d_in, const int* in_sizes, int n_in,
                              void* d_out, int out_size, void* d_ws, size_t ws_size,
                              hipStream_t stream) {
  const float2* act  = (const float2*)d_in[0];
  const float2* wts  = (const float2*)d_in[1];
  const float*  mstd = (const float*)d_in[2];
  float* outf = (float*)d_out;
  (void)in_sizes; (void)n_in; (void)out_size;

  GMeta gm; CMeta cm; MPar mp;
  for (int l=0;l<6;++l){ gm.mt[l]=MT[l]; gm.K[l]=2*MT[l]; }
  for (int l=0;l<7;++l) gm.ms_off[l]=MSOFF[l];
  for (int l=0;l<6;++l) gm.w_off[l]=24*gm.ms_off[l];
  int atot=0;
  for (int l=0;l<6;++l){ gm.aoff[l]=atot; atot+=48*gm.K[l]; }
  for (int i=0;i<NTRI;++i){
    cm.l1[i]=(unsigned char)TB.l1[i]; cm.l2[i]=(unsigned char)TB.l2[i];
    cm.lo[i]=(unsigned char)TB.lo[i]; cm.cg_off[i]=TB.cgoff[i];
    mp.gch[i]=MSOFF[TB.lo[i]]+TB.tpos[i]*576;
  }
  int ncg=TB.ncg;

  // heavy-first block order
  {
    int ordt[NTRI];
    for (int i=0;i<NTRI;++i) ordt[i]=i;
    for (int i=1;i<NTRI;++i){
      int v=ordt[i];
      int wv=(2*TB.lo[v]+1)*(2*TB.l1[v]+1);
      int j=i-1;
      while (j>=0){
        int wj=(2*TB.lo[ordt[j]]+1)*(2*TB.l1[ordt[j]]+1);
        if (wj>=wv) break;
        ordt[j+1]=ordt[j]; --j;
      }
      ordt[j+1]=v;
    }
    for (int i=0;i<NTRI;++i) mp.otri[i]=(unsigned char)ordt[i];
  }

  // ---- ws layout ----
  size_t ob=0;
  auto alloc=[&](size_t bytes){ size_t o=ob; ob=(ob+bytes+255)&~255ULL; return o; };
  size_t off_cg      = alloc((size_t)ncg*4);
  size_t off_partial = alloc((size_t)NB*MS_LEN*4);
  size_t off_A       = alloc((size_t)atot*2);
  size_t off_part    = alloc((size_t)288*4*768*4);
  size_t off_B       = ob;

  size_t perB=0;
  for (int l=0;l<6;++l) perB += (size_t)(2*l+1)*gm.K[l]*2;
  int nb=16;
  for (int cand : {128,64,32,16})
    if (off_B + (size_t)cand*perB <= ws_size){ nb=cand; break; }

  { int bo=0; for (int l=0;l<6;++l){ gm.boff[l]=bo; bo+=nb*(2*l+1)*gm.K[l]; } }
  gm.tb[0]=0;
  for (int l=0;l<6;++l) gm.tb[l+1]=gm.tb[l]+nb*(2*l+1)/16;
  for (int i=0;i<NTRI;++i)
    mp.bb[i] = gm.boff[TB.lo[i]] + TB.tpos[i]*1152;   // column base, interleaved K

  uint8_t* wsb=(uint8_t*)d_ws;
  float* cg      =(float*)(wsb+off_cg);
  float* partial =(float*)(wsb+off_partial);
  bf16*  Am      =(bf16*)(wsb+off_A);
  float* part    =(float*)(wsb+off_part);
  bf16*  Bm      =(bf16*)(wsb+off_B);

  k_init_cg<<<NTRI,64,0,stream>>>(cg, cm);
  int tiles=gm.tb[6];
  if (nb==NB){
    k_mid3<<<dim3(NTRI,NB),576,0,stream>>>(act,cg,Bm,partial,mp,0);
    k_scaleA<<<(MS_LEN+255)/256,256,0,stream>>>(partial,mstd,wts,Am,gm);
    k_gemm2<<<dim3(tiles,4),256,0,stream>>>(Am,Bm,part,gm);
    k_red<<<tiles,256,0,stream>>>(part,outf,gm,0);
  } else {
    for (int b0=0;b0<NB;b0+=nb)
      k_mid3<<<dim3(NTRI,nb),576,0,stream>>>(act,cg,Bm,partial,mp,b0);
    k_scaleA<<<(MS_LEN+255)/256,256,0,stream>>>(partial,mstd,wts,Am,gm);
    for (int b0=0;b0<NB;b0+=nb){
      k_mid3<<<dim3(NTRI,nb),576,0,stream>>>(act,cg,Bm,partial,mp,b0);
      k_gemm2<<<dim3(tiles,4),256,0,stream>>>(Am,Bm,part,gm);
      k_red<<<tiles,256,0,stream>>>(part,outf,gm,b0);
    }
  }
}

// Round 12
// 146.283 us; speedup vs baseline: 2.1139x; 1.3168x over previous
//
#include <hip/hip_runtime.h>
#include <hip/hip_bf16.h>
#include <math.h>

#define NTRI 69
#define NB 128
#define IN_LEN 864
#define MS_LEN 39744
#define EPSV 1e-5f

typedef short short8 __attribute__((ext_vector_type(8)));
typedef float f32x4 __attribute__((ext_vector_type(4)));
typedef __hip_bfloat16 bf16;

// ---- compile-time triple tables ----
struct Tables { int l1[NTRI], l2[NTRI], lo[NTRI], tpos[NTRI]; };
constexpr Tables make_tables(){
  Tables t{};
  int cnt[6]={0,0,0,0,0,0}; int n=0;
  for(int a=0;a<=5;++a)
    for(int b=0;b<=a;++b)
      for(int l=a-b; l<=((a+b<5)?(a+b):5); ++l){
        t.l1[n]=a; t.l2[n]=b; t.lo[n]=l; t.tpos[n]=cnt[l]++; ++n;
      }
  return t;
}
constexpr Tables TB = make_tables();
constexpr int MT[6]   = {3456,5760,7488,8064,8064,6912};
constexpr int MSOFF[7]= {0,3456,9216,16704,24768,32832,39744};

// ---- compile-time Clebsch-Gordan ----
constexpr double cfac(int n){ double f=1.0; for(int i=2;i<=n;++i) f*=(double)i; return f; }
constexpr double csqrt_(double x){
  if (x<=0.0) return 0.0;
  double g = x>1.0 ? x : 1.0;
  for (int i=0;i<100;++i) g = 0.5*(g + x/g);
  return g;
}
constexpr double cg_c(int j1,int m1,int j2,int m2,int j,int m){
  if (m1+m2!=m) return 0.0;
  double pref = csqrt_((2.0*j+1.0)*cfac(j+j1-j2)*cfac(j-j1+j2)*cfac(j1+j2-j)/cfac(j1+j2+j+1));
  pref *= csqrt_(cfac(j+m)*cfac(j-m)*cfac(j1-m1)*cfac(j1+m1)*cfac(j2-m2)*cfac(j2+m2));
  int kmin = 0;
  if (-(j-j2+m1) > kmin) kmin = -(j-j2+m1);
  if (-(j-j1-m2) > kmin) kmin = -(j-j1-m2);
  int kmax = j1+j2-j;
  if (j1-m1 < kmax) kmax = j1-m1;
  if (j2+m2 < kmax) kmax = j2+m2;
  double s = 0.0;
  for (int k=kmin;k<=kmax;++k){
    double d = cfac(k)*cfac(j1+j2-j-k)*cfac(j1-m1-k)*cfac(j2+m2-k)*cfac(j-j2+m1+k)*cfac(j-j1-m2+k);
    s += ((k&1)? -1.0:1.0)/d;
  }
  return pref*s;
}

// compile-time for
template<int I> struct Int { static constexpr int v = I; };
template<int B,int E,class F>
__device__ __forceinline__ void cfor(F f){
  if constexpr (B<E){ f(Int<B>{}); cfor<B+1,E>(f); }
}

struct MPar {
  int bb[NTRI];                 // B column base (elements): boff[l]+tpos*1152 (interleaved K)
  int gch[NTRI];                // global middle-channel base
  unsigned char otri[NTRI];     // heavy-first block order
};
struct GMeta { int aoff[6], boff[6], K[6], mt[6], w_off[6], ms_off[7], tb[7]; };

// ---- per-TRIPLE middle kernel: R6 geometry, CG baked as literals ----
// one thread = (channel, 1 batch); no LDS, no syncthreads.
template<int TRI>
__device__ __forceinline__ void mid_body(
    const float2* __restrict__ act,
    bf16* __restrict__ Bm, float* __restrict__ partial,
    const MPar& mp, int ts, int b0)
{
  constexpr int L1=TB.l1[TRI], L2=TB.l2[TRI], L=TB.lo[TRI];
  constexpr int N1=2*L1+1, N2=2*L2+1, NM=2*L+1;
  constexpr int D=L1+L2-L;
  constexpr int MTL=MT[L], KL=2*MTL;
  int t=ts/24, s=ts-24*t;
  const int a1=24*L1*L1+t*N1, a2=24*L2*L2+s*N2;
  const int brel=(int)blockIdx.y;
  const int b=b0+brel;
  const float2* ab=act+(size_t)b*IN_LEN;
  float f1r[N1],f1i[N1],f2r[N2],f2i[N2];
  cfor<0,N1>([&](auto X){ constexpr int x=decltype(X)::v;
    float2 v=ab[a1+x]; f1r[x]=v.x; f1i[x]=v.y; });
  cfor<0,N2>([&](auto Y){ constexpr int y=decltype(Y)::v;
    float2 v=ab[a2+y]; f2r[y]=v.x; f2i[y]=v.y; });
  float ss=0.f;
  size_t rowb=(size_t)mp.bb[TRI]+(size_t)brel*NM*KL+2*ts;
  cfor<0,NM>([&](auto M_){
    constexpr int m=decltype(M_)::v;
    float fr=0.f, fi=0.f;
    cfor<0,N1>([&](auto X){
      constexpr int x=decltype(X)::v;
      constexpr int y=m-x+D;
      if constexpr (y>=0 && y<N2){
        constexpr float cv=(float)cg_c(L1,x-L1,L2,y-L2,L,m-L);
        if constexpr (cv!=0.f){
          fr += cv*(f1r[x]*f2r[y]-f1i[x]*f2i[y]);
          fi += cv*(f1r[x]*f2i[y]+f1i[x]*f2r[y]);
        }
      }
    });
    ss += fr*fr+fi*fi;
    union { bf16 h[2]; unsigned u; } pk;
    pk.h[0]=__float2bfloat16(fr); pk.h[1]=__float2bfloat16(fi);
    *reinterpret_cast<unsigned*>(Bm+rowb+(size_t)m*KL)=pk.u;
  });
  partial[(size_t)b*MS_LEN + mp.gch[TRI] + ts] = ss;
}

__global__ __launch_bounds__(192,4)
void k_mid3(const float2* __restrict__ act,
            bf16* __restrict__ Bm, float* __restrict__ partial, MPar mp, int b0){
  int bx=blockIdx.x;
  int tri = mp.otri[bx/3], seg = bx - (bx/3)*3;
  int ts = seg*192 + threadIdx.x;
  #define CASE(T) case T: mid_body<T>(act,Bm,partial,mp,ts,b0); break;
  switch(tri){
    CASE(0) CASE(1) CASE(2) CASE(3) CASE(4) CASE(5) CASE(6) CASE(7) CASE(8)
    CASE(9) CASE(10) CASE(11) CASE(12) CASE(13) CASE(14) CASE(15) CASE(16)
    CASE(17) CASE(18) CASE(19) CASE(20) CASE(21) CASE(22) CASE(23) CASE(24)
    CASE(25) CASE(26) CASE(27) CASE(28) CASE(29) CASE(30) CASE(31) CASE(32)
    CASE(33) CASE(34) CASE(35) CASE(36) CASE(37) CASE(38) CASE(39) CASE(40)
    CASE(41) CASE(42) CASE(43) CASE(44) CASE(45) CASE(46) CASE(47) CASE(48)
    CASE(49) CASE(50) CASE(51) CASE(52) CASE(53) CASE(54) CASE(55) CASE(56)
    CASE(57) CASE(58) CASE(59) CASE(60) CASE(61) CASE(62) CASE(63) CASE(64)
    CASE(65) CASE(66) CASE(67) CASE(68)
    default: break;
  }
  #undef CASE
}

// fused: per-channel scale computation + scaled stacked-real A build
__global__ __launch_bounds__(256)
void k_scaleA(const float* __restrict__ partial, const float* __restrict__ mstd,
              const float2* __restrict__ wts, bf16* __restrict__ Am, GMeta gm){
  int c=blockIdx.x*256+threadIdx.x;
  if (c>=MS_LEN) return;
  int l=0;
  #pragma unroll
  for (int i=1;i<6;++i) if (c>=gm.ms_off[i]) l=i;
  float ss=0.f;
  for (int g=0;g<NB;++g) ss += partial[(size_t)g*MS_LEN+c];
  float bstd = sqrtf(ss/(128.f*(float)(2*l+1)));
  float s = 1.f/(0.5f*(mstd[c]+bstd)+EPSV);
  int mt=gm.mt[l];
  int cl=c-gm.ms_off[l];
  size_t K=(size_t)gm.K[l];
  bf16* Al=Am+gm.aoff[l];
  const float2* Wl=wts+gm.w_off[l];
  #pragma unroll 4
  for (int o=0;o<24;++o){
    float2 w=Wl[(size_t)o*mt+cl];
    union { bf16 h[2]; unsigned u; } p0, p1;
    p0.h[0]=__float2bfloat16(w.x*s);  p0.h[1]=__float2bfloat16(-w.y*s);
    p1.h[0]=__float2bfloat16(w.y*s);  p1.h[1]=__float2bfloat16(w.x*s);
    *reinterpret_cast<unsigned*>(Al+(size_t)o*K+2*cl)      = p0.u;
    *reinterpret_cast<unsigned*>(Al+(size_t)(24+o)*K+2*cl) = p1.u;
  }
}

// GEMM with K split over blockIdx.y into 4 chunks; per-chunk 48x16 tile -> part
__global__ __launch_bounds__(256)
void k_gemm2(const bf16* __restrict__ Am, const bf16* __restrict__ Bm,
             float* __restrict__ part, GMeta gm){
  int bid=blockIdx.x, z=blockIdx.y;
  int l=0;
  #pragma unroll
  for (int i=1;i<6;++i) if (bid>=gm.tb[i]) l=i;
  int ntile=bid-gm.tb[l];
  int K=gm.K[l];
  int tid=threadIdx.x, lane=tid&63, w=tid>>6;
  int r=lane&15, kg=lane>>4;
  int nit=K>>7;
  int nz=(nit+3)>>2;
  int it0=z*nz, it1=(nit<it0+nz)?nit:(it0+nz);
  f32x4 acc0={0.f,0.f,0.f,0.f}, acc1=acc0, acc2=acc0;
  __shared__ float red[3072];
  if (it0<it1){
    const bf16* Al=Am+gm.aoff[l];
    const bf16* Bl=Bm+gm.boff[l];
    size_t koff=(size_t)(w*32+kg*8)+(size_t)it0*128;
    const short8* pa0=(const short8*)(Al+(size_t)r*K+koff);
    const short8* pa1=(const short8*)(Al+(size_t)(16+r)*K+koff);
    const short8* pa2=(const short8*)(Al+(size_t)(32+r)*K+koff);
    const short8* pb =(const short8*)(Bl+(size_t)(ntile*16+r)*K+koff);
    short8 ca0=*pa0, ca1=*pa1, ca2=*pa2, cb=*pb;
    for (int it=it0+1; it<it1; ++it){
      pa0+=16; pa1+=16; pa2+=16; pb+=16;
      short8 na0=*pa0, na1=*pa1, na2=*pa2, nb_=*pb;
      acc0=__builtin_amdgcn_mfma_f32_16x16x32_bf16(ca0,cb,acc0,0,0,0);
      acc1=__builtin_amdgcn_mfma_f32_16x16x32_bf16(ca1,cb,acc1,0,0,0);
      acc2=__builtin_amdgcn_mfma_f32_16x16x32_bf16(ca2,cb,acc2,0,0,0);
      ca0=na0; ca1=na1; ca2=na2; cb=nb_;
    }
    acc0=__builtin_amdgcn_mfma_f32_16x16x32_bf16(ca0,cb,acc0,0,0,0);
    acc1=__builtin_amdgcn_mfma_f32_16x16x32_bf16(ca1,cb,acc1,0,0,0);
    acc2=__builtin_amdgcn_mfma_f32_16x16x32_bf16(ca2,cb,acc2,0,0,0);
  }
  #pragma unroll
  for (int reg=0;reg<4;++reg){
    int row0=kg*4+reg;
    red[(w*48+row0)*16+r]     =acc0[reg];
    red[(w*48+16+row0)*16+r]  =acc1[reg];
    red[(w*48+32+row0)*16+r]  =acc2[reg];
  }
  __syncthreads();
  float* po = part + (size_t)(bid*4+z)*768;
  for (int e=tid;e<768;e+=256)
    po[e]=red[e]+red[768+e]+red[1536+e]+red[2304+e];
}

__global__ __launch_bounds__(256)
void k_red(const float* __restrict__ part, float* __restrict__ outf,
           GMeta gm, int b0){
  int bid=blockIdx.x;
  int l=0;
  #pragma unroll
  for (int i=1;i<6;++i) if (bid>=gm.tb[i]) l=i;
  int ntile=bid-gm.tb[l];
  int nm=2*l+1;
  const float* po = part + (size_t)bid*4*768;
  for (int e=threadIdx.x;e<768;e+=256){
    float sv=po[e]+po[768+e]+po[1536+e]+po[2304+e];
    int o=e>>4, cc=e&15;
    int n=ntile*16+cc;
    int bb=n/nm, m=n-bb*nm;
    int b=b0+bb;
    int oo=(o<24)?o:(o-24);
    int comp=(o<24)?0:1;
    outf[((size_t)b*IN_LEN + 24*l*l + oo*nm + m)*2 + comp]=sv;
  }
}

extern "C" void kernel_launch(void* const* d_in, const int* in_sizes, int n_in,
                              void* d_out, int out_size, void* d_ws, size_t ws_size,
                              hipStream_t stream) {
  const float2* act  = (const float2*)d_in[0];
  const float2* wts  = (const float2*)d_in[1];
  const float*  mstd = (const float*)d_in[2];
  float* outf = (float*)d_out;
  (void)in_sizes; (void)n_in; (void)out_size;

  GMeta gm; MPar mp;
  for (int l=0;l<6;++l){ gm.mt[l]=MT[l]; gm.K[l]=2*MT[l]; }
  for (int l=0;l<7;++l) gm.ms_off[l]=MSOFF[l];
  for (int l=0;l<6;++l) gm.w_off[l]=24*gm.ms_off[l];
  int atot=0;
  for (int l=0;l<6;++l){ gm.aoff[l]=atot; atot+=48*gm.K[l]; }
  for (int i=0;i<NTRI;++i)
    mp.gch[i]=MSOFF[TB.lo[i]]+TB.tpos[i]*576;

  // heavy-first block order
  {
    int ordt[NTRI];
    for (int i=0;i<NTRI;++i) ordt[i]=i;
    for (int i=1;i<NTRI;++i){
      int v=ordt[i];
      int wv=(2*TB.lo[v]+1)*(2*TB.l1[v]+1);
      int j=i-1;
      while (j>=0){
        int wj=(2*TB.lo[ordt[j]]+1)*(2*TB.l1[ordt[j]]+1);
        if (wj>=wv) break;
        ordt[j+1]=ordt[j]; --j;
      }
      ordt[j+1]=v;
    }
    for (int i=0;i<NTRI;++i) mp.otri[i]=(unsigned char)ordt[i];
  }

  // ---- ws layout ----
  size_t ob=0;
  auto alloc=[&](size_t bytes){ size_t o=ob; ob=(ob+bytes+255)&~255ULL; return o; };
  size_t off_partial = alloc((size_t)NB*MS_LEN*4);
  size_t off_A       = alloc((size_t)atot*2);
  size_t off_part    = alloc((size_t)288*4*768*4);
  size_t off_B       = ob;

  size_t perB=0;
  for (int l=0;l<6;++l) perB += (size_t)(2*l+1)*gm.K[l]*2;
  int nb=16;
  for (int cand : {128,64,32,16})
    if (off_B + (size_t)cand*perB <= ws_size){ nb=cand; break; }

  { int bo=0; for (int l=0;l<6;++l){ gm.boff[l]=bo; bo+=nb*(2*l+1)*gm.K[l]; } }
  gm.tb[0]=0;
  for (int l=0;l<6;++l) gm.tb[l+1]=gm.tb[l]+nb*(2*l+1)/16;
  for (int i=0;i<NTRI;++i)
    mp.bb[i] = gm.boff[TB.lo[i]] + TB.tpos[i]*1152;   // column base, interleaved K

  uint8_t* wsb=(uint8_t*)d_ws;
  float* partial =(float*)(wsb+off_partial);
  bf16*  Am      =(bf16*)(wsb+off_A);
  float* part    =(float*)(wsb+off_part);
  bf16*  Bm      =(bf16*)(wsb+off_B);

  int tiles=gm.tb[6];
  if (nb==NB){
    k_mid3<<<dim3(NTRI*3,NB),192,0,stream>>>(act,Bm,partial,mp,0);
    k_scaleA<<<(MS_LEN+255)/256,256,0,stream>>>(partial,mstd,wts,Am,gm);
    k_gemm2<<<dim3(tiles,4),256,0,stream>>>(Am,Bm,part,gm);
    k_red<<<tiles,256,0,stream>>>(part,outf,gm,0);
  } else {
    for (int b0=0;b0<NB;b0+=nb)
      k_mid3<<<dim3(NTRI*3,nb),192,0,stream>>>(act,Bm,partial,mp,b0);
    k_scaleA<<<(MS_LEN+255)/256,256,0,stream>>>(partial,mstd,wts,Am,gm);
    for (int b0=0;b0<NB;b0+=nb){
      k_mid3<<<dim3(NTRI*3,nb),192,0,stream>>>(act,Bm,partial,mp,b0);
      k_gemm2<<<dim3(tiles,4),256,0,stream>>>(Am,Bm,part,gm);
      k_red<<<tiles,256,0,stream>>>(part,outf,gm,b0);
    }
  }
}